// Round 1
// baseline (1031.128 us; speedup 1.0000x reference)
//
#include <hip/hip_runtime.h>
#include <cstdint>
#include <cstddef>

// ---------------------------------------------------------------------------
// AKT-style 6-layer transformer forward on MI355X (gfx950).
// B=32 S=512 D=256 H=8 DK=32 DFF=1024, L=6 params stacked on axis 0.
// Strategy: bf16 MFMA GEMMs (128x128 tile, global_load_lds staging),
// swapped-QK^T MFMA attention with in-register softmax/cumsum/decay,
// fp32 residual stream + LN. ws usage ~131 MB.
// ---------------------------------------------------------------------------

#define AS1 __attribute__((address_space(1)))
#define AS3 __attribute__((address_space(3)))

typedef __bf16 bf16;
typedef __bf16 bf16x8 __attribute__((ext_vector_type(8)));
typedef __bf16 bf16x4 __attribute__((ext_vector_type(4)));
typedef float  f32x4  __attribute__((ext_vector_type(4)));
typedef unsigned int u32;

static constexpr int Bc = 32, Sc = 512, Dc = 256, Hc = 8, DKc = 32, DFFc = 1024;
static constexpr int Mc = Bc * Sc; // 16384 rows

// ---------------------------------------------------------------- converts
__global__ void cvt_copy_kernel(const float* __restrict__ src, float* __restrict__ d32,
                                bf16* __restrict__ d16, int n) {
  for (int i = blockIdx.x * blockDim.x + threadIdx.x; i < n; i += gridDim.x * blockDim.x) {
    float v = src[i];
    d32[i] = v;
    d16[i] = (bf16)v;
  }
}

// W [K,N] fp32 -> Wt [N,K] bf16, per layer slice (blockIdx.y)
__global__ void transpose_cvt_kernel(const float* __restrict__ src, bf16* __restrict__ dst,
                                     int K, int N) {
  size_t base = (size_t)blockIdx.y * K * N;
  int total = K * N;
  for (int idx = blockIdx.x * blockDim.x + threadIdx.x; idx < total; idx += gridDim.x * blockDim.x) {
    int k = idx / N, n = idx - k * N;
    dst[base + (size_t)n * K + k] = (bf16)src[base + idx];
  }
}

// ---------------------------------------------------------------- GEMM
// C[M,N] = A[M,K](bf16) @ Bt[N,K]^T (bf16) + bias, optional relu.
// 128x128 tile, BK=32, 4 waves (2x2), 16x16x32 MFMA, global_load_lds width 16.
template <int RELU, typename OUT_T>
__global__ __launch_bounds__(256) void gemm_bias_kernel(
    const bf16* __restrict__ A, const bf16* __restrict__ Bt,
    const float* __restrict__ bias, OUT_T* __restrict__ C, int K, int N) {
  __shared__ bf16 As[128 * 32];
  __shared__ bf16 Bs[128 * 32];
  const int tid = threadIdx.x;
  const int lane = tid & 63;
  const int wid = tid >> 6;
  const int m0 = blockIdx.x * 128;
  const int n0 = blockIdx.y * 128;
  const int wm = (wid >> 1) * 64;
  const int wn = (wid & 1) * 64;
  f32x4 acc[4][4] = {};

  const int o1 = wid * 1024 + lane * 16;
  const int o2 = o1 + 4096;
  const int r1 = o1 >> 6, c1 = o1 & 63;
  const int r2 = o2 >> 6, c2 = o2 & 63;
  const char* Ab = (const char*)A;
  const char* Bb = (const char*)Bt;
  const size_t stride = (size_t)K * 2;

  for (int k0 = 0; k0 < K; k0 += 32) {
    const char* a1 = Ab + (size_t)(m0 + r1) * stride + (size_t)k0 * 2 + c1;
    const char* a2 = Ab + (size_t)(m0 + r2) * stride + (size_t)k0 * 2 + c2;
    const char* b1 = Bb + (size_t)(n0 + r1) * stride + (size_t)k0 * 2 + c1;
    const char* b2 = Bb + (size_t)(n0 + r2) * stride + (size_t)k0 * 2 + c2;
    __builtin_amdgcn_global_load_lds((const AS1 u32*)a1, (AS3 u32*)((char*)As + wid * 1024), 16, 0, 0);
    __builtin_amdgcn_global_load_lds((const AS1 u32*)a2, (AS3 u32*)((char*)As + wid * 1024 + 4096), 16, 0, 0);
    __builtin_amdgcn_global_load_lds((const AS1 u32*)b1, (AS3 u32*)((char*)Bs + wid * 1024), 16, 0, 0);
    __builtin_amdgcn_global_load_lds((const AS1 u32*)b2, (AS3 u32*)((char*)Bs + wid * 1024 + 4096), 16, 0, 0);
    asm volatile("s_waitcnt vmcnt(0)" ::: "memory");
    __syncthreads();

    const int rr = lane & 15;
    const int g8 = (lane >> 4) * 8;
    bf16x8 af[4], bfr[4];
#pragma unroll
    for (int i = 0; i < 4; ++i) {
      af[i]  = *(const bf16x8*)&As[(wm + i * 16 + rr) * 32 + g8];
      bfr[i] = *(const bf16x8*)&Bs[(wn + i * 16 + rr) * 32 + g8];
    }
#pragma unroll
    for (int mi = 0; mi < 4; ++mi)
#pragma unroll
      for (int ni = 0; ni < 4; ++ni)
        acc[mi][ni] = __builtin_amdgcn_mfma_f32_16x16x32_bf16(af[mi], bfr[ni], acc[mi][ni], 0, 0, 0);
    __syncthreads();
  }

  const int rr = lane & 15;
  const int g4 = (lane >> 4) * 4;
  float bv[4];
#pragma unroll
  for (int ni = 0; ni < 4; ++ni) bv[ni] = bias[n0 + wn + ni * 16 + rr];
#pragma unroll
  for (int mi = 0; mi < 4; ++mi)
#pragma unroll
    for (int ni = 0; ni < 4; ++ni)
#pragma unroll
      for (int r = 0; r < 4; ++r) {
        float v = acc[mi][ni][r] + bv[ni];
        if (RELU) v = fmaxf(v, 0.f);
        int row = m0 + wm + mi * 16 + g4 + r;
        int col = n0 + wn + ni * 16 + rr;
        C[(size_t)row * N + col] = (OUT_T)v;
      }
}

// ---------------------------------------------------------------- attention
// Per block: one (b,h), one row-half (even/odd 16-row q-blocks). 512 threads.
// kh==qh (kq_same). Swapped QK^T: lane q=lane&15 owns one q-row; j spread over
// 4 partner lanes {q,q+16,q+32,q+48} x 4 regs per 16-j tile.
__global__ __launch_bounds__(512, 2) void attn_kernel(
    const bf16* __restrict__ kh, const bf16* __restrict__ vh,
    const float* __restrict__ gam, bf16* __restrict__ o, int incl_diag) {
  __shared__ bf16 Klds[512 * 32];     // [j][dk] linear (matches global_load_lds)
  __shared__ bf16 Vt[32 * 520];       // [dk][j] pad 520
  __shared__ bf16 astage[8][512];     // per-wave [16 q][32 j] prob restage

  const int tid = threadIdx.x;
  const int lane = tid & 63;
  const int wid = tid >> 6;
  const int bh = blockIdx.x;
  const int half = blockIdx.y;
  const int b = bh >> 3, h = bh & 7;
  const bf16* kbase = kh + ((size_t)b * 4096 + h) * 32;  // row j at + j*256 elems
  const bf16* vbase = vh + ((size_t)b * 4096 + h) * 32;

  // stage K: 32 KB via global_load_lds (linear [512][32] bf16, row = 64 B)
#pragma unroll
  for (int it = 0; it < 4; ++it) {
    int off = it * 8192 + wid * 1024 + lane * 16;
    int j = off >> 6;
    int cc = off & 63;
    const char* g = (const char*)kbase + (size_t)j * 512 + cc;
    __builtin_amdgcn_global_load_lds((const AS1 u32*)g,
                                     (AS3 u32*)((char*)Klds + it * 8192 + wid * 1024), 16, 0, 0);
  }
  // stage V transposed: Vt[dk][j]
#pragma unroll
  for (int it = 0; it < 4; ++it) {
    int task = it * 512 + tid;
    int j = task & 511;
    int cc = task >> 9;  // 0..3 (8-elem chunk of dk)
    bf16x8 v = *(const bf16x8*)(vbase + (size_t)j * 256 + cc * 8);
#pragma unroll
    for (int e = 0; e < 8; ++e) Vt[(cc * 8 + e) * 520 + j] = v[e];
  }
  asm volatile("s_waitcnt vmcnt(0)" ::: "memory");
  __syncthreads();

  const float scale = 0.17677669529663687f;  // 1/sqrt(32)
  float gm = gam[h];
  float gneg = -(fmaxf(gm, 0.f) + log1pf(__expf(-fabsf(gm))));

  const int q = lane & 15;
  const int g = lane >> 4;

#pragma unroll
  for (int t = 0; t < 2; ++t) {
    const int qb = half + 2 * (wid + 8 * t);  // q-block 0..31
    const int q0 = qb * 16;
    const int qr = q0 + q;
    const int qlim = incl_diag ? qr : (qr - 1);
    int jtN = qb + 1;
    jtN = (jtN + 1) & ~1;  // even # of 16-j tiles

    const bf16x8 qf = *(const bf16x8*)&Klds[(size_t)(q0 + q) * 32 + g * 8];

    // pass A: unnormalized softmax total (no max-sub needed: |s| <~ 6)
    float tot = 0.f;
    for (int jt = 0; jt < jtN; ++jt) {
      bf16x8 af = *(const bf16x8*)&Klds[(size_t)(jt * 16 + q) * 32 + g * 8];
      f32x4 c = {0.f, 0.f, 0.f, 0.f};
      c = __builtin_amdgcn_mfma_f32_16x16x32_bf16(af, qf, c, 0, 0, 0);
#pragma unroll
      for (int r = 0; r < 4; ++r) {
        int j = jt * 16 + 4 * g + r;
        tot += (j <= qlim) ? __expf(c[r] * scale) : 0.f;
      }
    }
    tot += __shfl_xor(tot, 16);
    tot += __shfl_xor(tot, 32);
    const float itot = tot > 0.f ? 1.f / tot : 0.f;

    // pass B: recompute scores; scan cumsum; decay; second softmax numerators
    bf16x8 pb[16];
    float run = 0.f, sum2 = 0.f;
#pragma unroll
    for (int jt = 0; jt < 32; ++jt) {
      if (jt >= jtN) break;
      bf16x8 af = *(const bf16x8*)&Klds[(size_t)(jt * 16 + q) * 32 + g * 8];
      f32x4 c = {0.f, 0.f, 0.f, 0.f};
      c = __builtin_amdgcn_mfma_f32_16x16x32_bf16(af, qf, c, 0, 0, 0);
      float s_[4], ee[4];
#pragma unroll
      for (int r = 0; r < 4; ++r) {
        int j = jt * 16 + 4 * g + r;
        s_[r] = c[r] * scale;
        ee[r] = (j <= qlim) ? __expf(s_[r]) : 0.f;
      }
      float lc[4];
      lc[0] = ee[0]; lc[1] = lc[0] + ee[1]; lc[2] = lc[1] + ee[2]; lc[3] = lc[2] + ee[3];
      float sc = lc[3];
      float u1 = __shfl_up(sc, 16); if (g >= 1) sc += u1;
      float u2 = __shfl_up(sc, 32); if (g >= 2) sc += u2;
      float excl = run + sc - lc[3];
      float ttot = __shfl(sc, q + 48);
      run += ttot;
#pragma unroll
      for (int r = 0; r < 4; ++r) {
        int j = jt * 16 + 4 * g + r;
        float cum = excl + lc[r];
        float pos = (float)(qr - j);
        float d2 = (1.f - cum * itot) * pos;
        float dist = sqrtf(fmaxf(d2, 0.f));
        float eff = fminf(fmaxf(__expf(dist * gneg), 1e-5f), 1e5f);
        float pv = (j <= qlim) ? __expf(s_[r] * eff) : 0.f;
        sum2 += pv;
        pb[jt >> 1][(jt & 1) * 4 + r] = (bf16)pv;
      }
    }
    sum2 += __shfl_xor(sum2, 16);
    sum2 += __shfl_xor(sum2, 32);
    const float inv2 = sum2 > 0.f ? 1.f / sum2 : 0.f;  // 0 => zero_pad row

    // pass C: PV via per-wave LDS restage (std-orientation A-frags)
    f32x4 oacc0 = {0.f, 0.f, 0.f, 0.f}, oacc1 = {0.f, 0.f, 0.f, 0.f};
    const int nch = jtN >> 1;
    bf16* ast = &astage[wid][0];
#pragma unroll
    for (int cch = 0; cch < 16; ++cch) {
      if (cch >= nch) break;
      uint4 pu = __builtin_bit_cast(uint4, pb[cch]);
      uint2 lo; lo.x = pu.x; lo.y = pu.y;
      uint2 hi; hi.x = pu.z; hi.y = pu.w;
      *(uint2*)&ast[q * 32 + 4 * g] = lo;        // j = 16*(2c) + 4g + r
      *(uint2*)&ast[q * 32 + 16 + 4 * g] = hi;   // j = 16*(2c+1) + 4g + r
      asm volatile("s_waitcnt lgkmcnt(0)" ::: "memory");
      __builtin_amdgcn_sched_barrier(0);
      bf16x8 afr = *(const bf16x8*)&ast[q * 32 + 8 * g];
      bf16x8 vb0 = *(const bf16x8*)&Vt[(size_t)q * 520 + cch * 32 + 8 * g];
      bf16x8 vb1 = *(const bf16x8*)&Vt[(size_t)(q + 16) * 520 + cch * 32 + 8 * g];
      oacc0 = __builtin_amdgcn_mfma_f32_16x16x32_bf16(afr, vb0, oacc0, 0, 0, 0);
      oacc1 = __builtin_amdgcn_mfma_f32_16x16x32_bf16(afr, vb1, oacc1, 0, 0, 0);
    }

    bf16* obase = o + ((size_t)b * 4096 + h) * 32;
#pragma unroll
    for (int r = 0; r < 4; ++r) {
      float iv = __shfl(inv2, 4 * g + r);
      int srow = q0 + 4 * g + r;
      obase[(size_t)srow * 256 + q] = (bf16)(oacc0[r] * iv);
      obase[(size_t)srow * 256 + 16 + q] = (bf16)(oacc1[r] * iv);
    }
  }
}

// ---------------------------------------------------------------- LayerNorm
// out = LN(resid + delta) * s + b ; writes fp32 + bf16 copies. Wave per row.
__global__ __launch_bounds__(256) void ln_kernel(
    const float* __restrict__ resid, const float* __restrict__ delta,
    const float* __restrict__ sc, const float* __restrict__ bi,
    float* __restrict__ out32, bf16* __restrict__ out16) {
  int row = blockIdx.x * 4 + (threadIdx.x >> 6);
  int lane = threadIdx.x & 63;
  const float4 x4 = *(const float4*)(resid + (size_t)row * 256 + lane * 4);
  const float4 d4 = *(const float4*)(delta + (size_t)row * 256 + lane * 4);
  float v[4] = {x4.x + d4.x, x4.y + d4.y, x4.z + d4.z, x4.w + d4.w};
  float s1 = v[0] + v[1] + v[2] + v[3];
  float s2 = v[0] * v[0] + v[1] * v[1] + v[2] * v[2] + v[3] * v[3];
#pragma unroll
  for (int off = 32; off; off >>= 1) {
    s1 += __shfl_xor(s1, off);
    s2 += __shfl_xor(s2, off);
  }
  float mu = s1 * (1.f / 256.f);
  float var = s2 * (1.f / 256.f) - mu * mu;
  float rs = rsqrtf(var + 1e-5f);
  const float4 sc4 = *(const float4*)(sc + lane * 4);
  const float4 bi4 = *(const float4*)(bi + lane * 4);
  float y0 = (v[0] - mu) * rs * sc4.x + bi4.x;
  float y1 = (v[1] - mu) * rs * sc4.y + bi4.y;
  float y2 = (v[2] - mu) * rs * sc4.z + bi4.z;
  float y3 = (v[3] - mu) * rs * sc4.w + bi4.w;
  float4 o4; o4.x = y0; o4.y = y1; o4.z = y2; o4.w = y3;
  *(float4*)(out32 + (size_t)row * 256 + lane * 4) = o4;
  bf16x4 ov = {(bf16)y0, (bf16)y1, (bf16)y2, (bf16)y3};
  *(bf16x4*)(out16 + (size_t)row * 256 + lane * 4) = ov;
}

// ---------------------------------------------------------------- host
extern "C" void kernel_launch(void* const* d_in, const int* in_sizes, int n_in,
                              void* d_out, int out_size, void* d_ws, size_t ws_size,
                              hipStream_t stream) {
  const float* q_embed  = (const float*)d_in[0];
  const float* qa_embed = (const float*)d_in[1];
  const float* Wk = (const float*)d_in[2];
  const float* bk = (const float*)d_in[3];
  const float* Wv = (const float*)d_in[4];
  const float* bv = (const float*)d_in[5];
  const float* Wo = (const float*)d_in[6];
  const float* bo = (const float*)d_in[7];
  const float* gammas = (const float*)d_in[8];
  const float* ln1_s = (const float*)d_in[9];
  const float* ln1_b = (const float*)d_in[10];
  const float* W1 = (const float*)d_in[11];
  const float* b1 = (const float*)d_in[12];
  const float* W2 = (const float*)d_in[13];
  const float* b2 = (const float*)d_in[14];
  const float* ln2_s = (const float*)d_in[15];
  const float* ln2_b = (const float*)d_in[16];
  float* out = (float*)d_out;

  char* ws = (char*)d_ws;
  float* y32 = (float*)(ws);
  float* x32 = (float*)(ws + ((size_t)16 << 20));
  bf16* y16  = (bf16*)(ws + ((size_t)32 << 20));
  bf16* x16  = (bf16*)(ws + ((size_t)40 << 20));
  bf16* khb  = (bf16*)(ws + ((size_t)48 << 20));
  bf16* vhb  = (bf16*)(ws + ((size_t)56 << 20));
  bf16* o16  = (bf16*)(ws + ((size_t)64 << 20));
  float* tmp32 = (float*)(ws + ((size_t)72 << 20));
  bf16* h116 = (bf16*)(ws + ((size_t)88 << 20));     // [M,1024] bf16 = 32 MB
  bf16* Wkt  = (bf16*)(ws + ((size_t)122 << 20));
  bf16* Wvt  = Wkt + 6 * 65536;
  bf16* Wot  = Wvt + 6 * 65536;
  bf16* W1t  = Wot + 6 * 65536;      // [N=1024][K=256] per layer
  bf16* W2t  = W1t + 6 * 262144;     // [N=256][K=1024] per layer

  transpose_cvt_kernel<<<dim3(64, 6), 256, 0, stream>>>(Wk, Wkt, 256, 256);
  transpose_cvt_kernel<<<dim3(64, 6), 256, 0, stream>>>(Wv, Wvt, 256, 256);
  transpose_cvt_kernel<<<dim3(64, 6), 256, 0, stream>>>(Wo, Wot, 256, 256);
  transpose_cvt_kernel<<<dim3(64, 6), 256, 0, stream>>>(W1, W1t, 256, 1024);
  transpose_cvt_kernel<<<dim3(64, 6), 256, 0, stream>>>(W2, W2t, 1024, 256);
  cvt_copy_kernel<<<2048, 256, 0, stream>>>(q_embed, x32, x16, Mc * Dc);
  cvt_copy_kernel<<<2048, 256, 0, stream>>>(qa_embed, y32, y16, Mc * Dc);

  const dim3 g256(128, 2);
  for (int i = 0; i < 6; ++i) {
    const bool first = (i < 2);
    const bool strict = (i == 3 || i == 5);   // mask_flag==0 layers
    const bool pos = first || strict;         // apply_pos
    bf16* in16 = first ? y16 : x16;           // q/k input (kq_same)
    bf16* v16  = (first || strict) ? y16 : x16;
    float* res32 = first ? y32 : x32;

    gemm_bias_kernel<0, bf16><<<g256, 256, 0, stream>>>(in16, Wkt + (size_t)i * 65536, bk + i * 256, khb, 256, 256);
    gemm_bias_kernel<0, bf16><<<g256, 256, 0, stream>>>(v16, Wvt + (size_t)i * 65536, bv + i * 256, vhb, 256, 256);
    attn_kernel<<<dim3(256, 2), 512, 0, stream>>>(khb, vhb, gammas + i * 8, o16, strict ? 0 : 1);
    gemm_bias_kernel<0, float><<<g256, 256, 0, stream>>>(o16, Wot + (size_t)i * 65536, bo + i * 256, tmp32, 256, 256);
    ln_kernel<<<4096, 256, 0, stream>>>(res32, tmp32, ln1_s + i * 256, ln1_b + i * 256, res32, in16);
    if (pos) {
      gemm_bias_kernel<1, bf16><<<dim3(128, 8), 256, 0, stream>>>(in16, W1t + (size_t)i * 262144, b1 + i * 1024, h116, 256, 1024);
      gemm_bias_kernel<0, float><<<g256, 256, 0, stream>>>(h116, W2t + (size_t)i * 262144, b2 + i * 256, tmp32, 1024, 256);
      float* fin = (i == 5) ? out : res32;
      ln_kernel<<<4096, 256, 0, stream>>>(res32, tmp32, ln2_s + i * 256, ln2_b + i * 256, fin, in16);
    }
  }
}

// Round 2
// 804.552 us; speedup vs baseline: 1.2816x; 1.2816x over previous
//
#include <hip/hip_runtime.h>
#include <cstdint>
#include <cstddef>

// ---------------------------------------------------------------------------
// AKT-style 6-layer transformer forward on MI355X (gfx950).  Round 2:
//  - attention: single QK^T pass (s stored as packed f16), balanced wave->qb
//    mapping, coalesced 16B output stores via LDS restage, b64 V-transpose,
//    padded astage.  Predicted: 131 MB -> ~42 MB traffic per dispatch.
//  - tiled LDS weight transpose (was 2B/512B-stride RMW writes).
//  - K+V projection merged into one 512-block GEMM launch.
// ---------------------------------------------------------------------------

#define AS1 __attribute__((address_space(1)))
#define AS3 __attribute__((address_space(3)))

typedef __bf16 bf16;
typedef __bf16 bf16x8 __attribute__((ext_vector_type(8)));
typedef __bf16 bf16x4 __attribute__((ext_vector_type(4)));
typedef _Float16 f16x4 __attribute__((ext_vector_type(4)));
typedef float  f32x4  __attribute__((ext_vector_type(4)));
typedef unsigned int u32;

static constexpr int Bc = 32, Sc = 512, Dc = 256, Hc = 8, DKc = 32, DFFc = 1024;
static constexpr int Mc = Bc * Sc; // 16384 rows

// ---------------------------------------------------------------- converts
__global__ void cvt_copy2_kernel(const float* __restrict__ s0, float* __restrict__ da32,
                                 bf16* __restrict__ da16, const float* __restrict__ s1,
                                 float* __restrict__ db32, bf16* __restrict__ db16, int n4) {
  const float* s = blockIdx.y ? s1 : s0;
  float* d32 = blockIdx.y ? db32 : da32;
  bf16* d16 = blockIdx.y ? db16 : da16;
  int i = blockIdx.x * blockDim.x + threadIdx.x;
  if (i < n4) {
    float4 v = ((const float4*)s)[i];
    ((float4*)d32)[i] = v;
    bf16x4 hx = {(bf16)v.x, (bf16)v.y, (bf16)v.z, (bf16)v.w};
    ((bf16x4*)d16)[i] = hx;
  }
}

// Tiled transpose+cvt for all 5 weights: W[K,N] fp32 -> Wt[N,K] bf16.
// 64x64 tile through LDS; reads float4 coalesced, writes bf16x4 coalesced.
__global__ __launch_bounds__(256) void transpose_cvt_all(
    const float* __restrict__ Wk, const float* __restrict__ Wv, const float* __restrict__ Wo,
    const float* __restrict__ W1, const float* __restrict__ W2,
    bf16* __restrict__ Wkt, bf16* __restrict__ Wvt, bf16* __restrict__ Wot,
    bf16* __restrict__ W1t, bf16* __restrict__ W2t) {
  int z = blockIdx.z;
  int layer = z % 6, w = z / 6;
  const float* src; bf16* dst; int K, N;
  switch (w) {
    case 0: src = Wk; dst = Wkt; K = 256; N = 256; break;
    case 1: src = Wv; dst = Wvt; K = 256; N = 256; break;
    case 2: src = Wo; dst = Wot; K = 256; N = 256; break;
    case 3: src = W1; dst = W1t; K = 256; N = 1024; break;
    default: src = W2; dst = W2t; K = 1024; N = 256; break;
  }
  int k0 = blockIdx.x * 64, n0 = blockIdx.y * 64;
  if (k0 >= K || n0 >= N) return;
  src += (size_t)layer * K * N;
  dst += (size_t)layer * K * N;
  __shared__ bf16 t[64][68];
  int tid = threadIdx.x;
  int rr = tid >> 4;         // 0..15
  int c4 = (tid & 15) * 4;   // 0..60
#pragma unroll
  for (int p = 0; p < 4; ++p) {
    int k = rr + p * 16;
    float4 v = *(const float4*)(src + (size_t)(k0 + k) * N + n0 + c4);
    t[c4 + 0][k] = (bf16)v.x;
    t[c4 + 1][k] = (bf16)v.y;
    t[c4 + 2][k] = (bf16)v.z;
    t[c4 + 3][k] = (bf16)v.w;
  }
  __syncthreads();
#pragma unroll
  for (int p = 0; p < 4; ++p) {
    int nl = rr + p * 16;
    bf16x4 o4 = *(const bf16x4*)&t[nl][c4];
    *(bf16x4*)(dst + (size_t)(n0 + nl) * K + k0 + c4) = o4;
  }
}

// ---------------------------------------------------------------- GEMM
// C[M,N] = A[M,K](bf16) @ Bt[N,K]^T (bf16) + bias, optional relu.
// 128x128 tile, BK=32, 4 waves (2x2), 16x16x32 MFMA, global_load_lds width 16.
template <int RELU, typename OUT_T>
__device__ __forceinline__ void gemm_body(
    const bf16* __restrict__ A, const bf16* __restrict__ Bt,
    const float* __restrict__ bias, OUT_T* __restrict__ C,
    int K, int N, int m0, int n0, bf16* As, bf16* Bs) {
  const int tid = threadIdx.x;
  const int lane = tid & 63;
  const int wid = tid >> 6;
  const int wm = (wid >> 1) * 64;
  const int wn = (wid & 1) * 64;
  f32x4 acc[4][4] = {};

  const int o1 = wid * 1024 + lane * 16;
  const int o2 = o1 + 4096;
  const int r1 = o1 >> 6, c1 = o1 & 63;
  const int r2 = o2 >> 6, c2 = o2 & 63;
  const char* Ab = (const char*)A;
  const char* Bb = (const char*)Bt;
  const size_t stride = (size_t)K * 2;

  for (int k0 = 0; k0 < K; k0 += 32) {
    const char* a1 = Ab + (size_t)(m0 + r1) * stride + (size_t)k0 * 2 + c1;
    const char* a2 = Ab + (size_t)(m0 + r2) * stride + (size_t)k0 * 2 + c2;
    const char* b1 = Bb + (size_t)(n0 + r1) * stride + (size_t)k0 * 2 + c1;
    const char* b2 = Bb + (size_t)(n0 + r2) * stride + (size_t)k0 * 2 + c2;
    __builtin_amdgcn_global_load_lds((const AS1 u32*)a1, (AS3 u32*)((char*)As + wid * 1024), 16, 0, 0);
    __builtin_amdgcn_global_load_lds((const AS1 u32*)a2, (AS3 u32*)((char*)As + wid * 1024 + 4096), 16, 0, 0);
    __builtin_amdgcn_global_load_lds((const AS1 u32*)b1, (AS3 u32*)((char*)Bs + wid * 1024), 16, 0, 0);
    __builtin_amdgcn_global_load_lds((const AS1 u32*)b2, (AS3 u32*)((char*)Bs + wid * 1024 + 4096), 16, 0, 0);
    asm volatile("s_waitcnt vmcnt(0)" ::: "memory");
    __syncthreads();

    const int rr = lane & 15;
    const int g8 = (lane >> 4) * 8;
    bf16x8 af[4], bfr[4];
#pragma unroll
    for (int i = 0; i < 4; ++i) {
      af[i]  = *(const bf16x8*)&As[(wm + i * 16 + rr) * 32 + g8];
      bfr[i] = *(const bf16x8*)&Bs[(wn + i * 16 + rr) * 32 + g8];
    }
#pragma unroll
    for (int mi = 0; mi < 4; ++mi)
#pragma unroll
      for (int ni = 0; ni < 4; ++ni)
        acc[mi][ni] = __builtin_amdgcn_mfma_f32_16x16x32_bf16(af[mi], bfr[ni], acc[mi][ni], 0, 0, 0);
    __syncthreads();
  }

  const int rr = lane & 15;
  const int g4 = (lane >> 4) * 4;
  float bv[4];
#pragma unroll
  for (int ni = 0; ni < 4; ++ni) bv[ni] = bias[n0 + wn + ni * 16 + rr];
#pragma unroll
  for (int mi = 0; mi < 4; ++mi)
#pragma unroll
    for (int ni = 0; ni < 4; ++ni)
#pragma unroll
      for (int r = 0; r < 4; ++r) {
        float v = acc[mi][ni][r] + bv[ni];
        if (RELU) v = fmaxf(v, 0.f);
        int row = m0 + wm + mi * 16 + g4 + r;
        int col = n0 + wn + ni * 16 + rr;
        C[(size_t)row * N + col] = (OUT_T)v;
      }
}

template <int RELU, typename OUT_T>
__global__ __launch_bounds__(256) void gemm_bias_kernel(
    const bf16* __restrict__ A, const bf16* __restrict__ Bt,
    const float* __restrict__ bias, OUT_T* __restrict__ C, int K, int N) {
  __shared__ bf16 As[128 * 32];
  __shared__ bf16 Bs[128 * 32];
  gemm_body<RELU, OUT_T>(A, Bt, bias, C, K, N, blockIdx.x * 128, blockIdx.y * 128, As, Bs);
}

// K and V projections in one launch: blockIdx.y 0..3, y>>1 selects K/V set.
__global__ __launch_bounds__(256) void gemm_kv_kernel(
    const bf16* __restrict__ A0, const bf16* __restrict__ Bt0,
    const float* __restrict__ b0, bf16* __restrict__ C0,
    const bf16* __restrict__ A1, const bf16* __restrict__ Bt1,
    const float* __restrict__ b1, bf16* __restrict__ C1, int K, int N) {
  __shared__ bf16 As[128 * 32];
  __shared__ bf16 Bs[128 * 32];
  int sel = blockIdx.y >> 1;
  gemm_body<0, bf16>(sel ? A1 : A0, sel ? Bt1 : Bt0, sel ? b1 : b0, sel ? C1 : C0,
                     K, N, blockIdx.x * 128, (blockIdx.y & 1) * 128, As, Bs);
}

// ---------------------------------------------------------------- attention
// Per block: one (b,h), one parity-half of q-blocks. 512 threads, 8 waves.
// Wave w handles q-blocks {half+2w, half+2(15-w)} (balanced tile counts).
// Single QK^T pass stores s (f16, -inf masked); fused scan/decay/PV pass;
// coalesced 16B output stores through LDS.
__global__ __launch_bounds__(512, 4) void attn_kernel(
    const bf16* __restrict__ kh, const bf16* __restrict__ vh,
    const float* __restrict__ gam, bf16* __restrict__ o, int incl_diag) {
  __shared__ bf16 Klds[512 * 32];      // [j][dk] linear (global_load_lds)
  __shared__ bf16 Vt[32 * 520];        // [dk][j], pad 520
  __shared__ bf16 astage[8][16 * 40];  // per-wave [16 q][32 j] pad 40

  const int tid = threadIdx.x;
  const int lane = tid & 63;
  const int wid = tid >> 6;
  const int bh = blockIdx.x;
  const int half = blockIdx.y;
  const int b = bh >> 3, h = bh & 7;
  const bf16* kbase = kh + ((size_t)b * 4096 + h) * 32;
  const bf16* vbase = vh + ((size_t)b * 4096 + h) * 32;
  bf16* obase = o + ((size_t)b * 4096 + h) * 32;

  // stage K: 32 KB via global_load_lds (linear [512][32] bf16, row = 64 B)
#pragma unroll
  for (int it = 0; it < 4; ++it) {
    int off = it * 8192 + wid * 1024 + lane * 16;
    int j = off >> 6, cc = off & 63;
    const char* gsrc = (const char*)kbase + (size_t)j * 512 + cc;
    __builtin_amdgcn_global_load_lds((const AS1 u32*)gsrc,
                                     (AS3 u32*)((char*)Klds + it * 8192 + wid * 1024), 16, 0, 0);
  }
  // stage V transposed with b64 LDS writes: thread owns j-quad x 8-dk chunk
  {
    int u = tid & 127;   // j quad index (j0 = 4u)
    int cg = tid >> 7;   // dk chunk 0..3
    const bf16* vb = vbase + (size_t)(4 * u) * 256 + cg * 8;
    bf16x8 r0 = *(const bf16x8*)(vb);
    bf16x8 r1 = *(const bf16x8*)(vb + 256);
    bf16x8 r2 = *(const bf16x8*)(vb + 512);
    bf16x8 r3 = *(const bf16x8*)(vb + 768);
#pragma unroll
    for (int e = 0; e < 8; ++e) {
      bf16x4 w4 = {r0[e], r1[e], r2[e], r3[e]};
      *(bf16x4*)&Vt[(size_t)(cg * 8 + e) * 520 + 4 * u] = w4;
    }
  }
  asm volatile("s_waitcnt vmcnt(0)" ::: "memory");
  __syncthreads();

  const float scale = 0.17677669529663687f;  // 1/sqrt(32)
  float gm = gam[h];
  float gneg = -(fmaxf(gm, 0.f) + log1pf(__expf(-fabsf(gm))));
  const float NINF = -__builtin_huge_valf();

  const int q = lane & 15;
  const int g = lane >> 4;
  bf16* ast = &astage[wid][0];

#pragma unroll
  for (int pass = 0; pass < 2; ++pass) {
    const int qb = half + 2 * (pass ? (15 - wid) : wid);  // balanced pairing
    const int q0 = qb * 16;
    const int qr = q0 + q;
    const int qlim = incl_diag ? qr : qr - 1;
    const int jtReal = qb + 1;
    const int jtN = (jtReal + 1) & ~1;  // even # of 16-j tiles

    const bf16x8 qf = *(const bf16x8*)&Klds[(size_t)(q0 + q) * 32 + g * 8];

    // Pass 1: QK^T, store s in f16 (masked -> -inf), accumulate raw total
    f16x4 tst[32];
    float tot = 0.f;
#pragma unroll
    for (int jt = 0; jt < 32; ++jt) {
      if (jt >= jtN) break;
      if (jt >= jtReal) {  // padding tile, fully masked
        f16x4 m;
        m[0] = m[1] = m[2] = m[3] = (_Float16)NINF;
        tst[jt] = m;
        continue;
      }
      bf16x8 af = *(const bf16x8*)&Klds[(size_t)(jt * 16 + q) * 32 + g * 8];
      f32x4 c = {0.f, 0.f, 0.f, 0.f};
      c = __builtin_amdgcn_mfma_f32_16x16x32_bf16(af, qf, c, 0, 0, 0);
#pragma unroll
      for (int r = 0; r < 4; ++r) {
        int j = jt * 16 + 4 * g + r;
        float sm = (j <= qlim) ? c[r] * scale : NINF;
        tst[jt][r] = (_Float16)sm;
        tot += __expf(sm);
      }
    }
    tot += __shfl_xor(tot, 16);
    tot += __shfl_xor(tot, 32);
    const float itot = tot > 0.f ? 1.f / tot : 0.f;

    // Pass 2: scan cumsum + decay + second-softmax numerators + PV, fused
    f32x4 oacc0 = {0.f, 0.f, 0.f, 0.f}, oacc1 = {0.f, 0.f, 0.f, 0.f};
    float run = 0.f, sum2 = 0.f;
#pragma unroll
    for (int cch = 0; cch < 16; ++cch) {
      if (cch * 2 >= jtN) break;
#pragma unroll
      for (int hf = 0; hf < 2; ++hf) {
        int jt = cch * 2 + hf;
        float su[4], ee[4];
#pragma unroll
        for (int r = 0; r < 4; ++r) {
          su[r] = (float)tst[jt][r];
          ee[r] = __expf(su[r]);
        }
        float lcs[4];
        lcs[0] = ee[0]; lcs[1] = lcs[0] + ee[1]; lcs[2] = lcs[1] + ee[2]; lcs[3] = lcs[2] + ee[3];
        float sc = lcs[3];
        float u1 = __shfl_up(sc, 16); if (g >= 1) sc += u1;
        float u2 = __shfl_up(sc, 32); if (g >= 2) sc += u2;
        float excl = run + sc - lcs[3];
        run += __shfl(sc, q + 48);
        float pv4[4];
#pragma unroll
        for (int r = 0; r < 4; ++r) {
          int j = jt * 16 + 4 * g + r;
          float cum = excl + lcs[r];
          float pos = (float)(qr - j);
          float d2 = (1.f - cum * itot) * pos;
          float dist = sqrtf(fmaxf(d2, 0.f));
          float eff = fminf(fmaxf(__expf(dist * gneg), 1e-5f), 1e5f);
          float pv = __expf(su[r] * eff);  // -inf * eff -> 0 for masked
          sum2 += pv;
          pv4[r] = pv;
        }
        bf16x4 pk = {(bf16)pv4[0], (bf16)pv4[1], (bf16)pv4[2], (bf16)pv4[3]};
        *(bf16x4*)&ast[q * 40 + hf * 16 + 4 * g] = pk;
      }
      asm volatile("s_waitcnt lgkmcnt(0)" ::: "memory");
      __builtin_amdgcn_sched_barrier(0);
      bf16x8 afr = *(const bf16x8*)&ast[q * 40 + 8 * g];
      bf16x8 vb0 = *(const bf16x8*)&Vt[(size_t)q * 520 + cch * 32 + 8 * g];
      bf16x8 vb1 = *(const bf16x8*)&Vt[(size_t)(q + 16) * 520 + cch * 32 + 8 * g];
      oacc0 = __builtin_amdgcn_mfma_f32_16x16x32_bf16(afr, vb0, oacc0, 0, 0, 0);
      oacc1 = __builtin_amdgcn_mfma_f32_16x16x32_bf16(afr, vb1, oacc1, 0, 0, 0);
    }
    sum2 += __shfl_xor(sum2, 16);
    sum2 += __shfl_xor(sum2, 32);
    const float inv2 = sum2 > 0.f ? 1.f / sum2 : 0.f;  // 0 => zero_pad row

    // epilogue: scale, restage in LDS, coalesced 16B stores (64B sectors)
#pragma unroll
    for (int r = 0; r < 4; ++r) {
      float iv = __shfl(inv2, 4 * g + r);
      int rl = 4 * g + r;
      ast[rl * 40 + q] = (bf16)(oacc0[r] * iv);
      ast[rl * 40 + 16 + q] = (bf16)(oacc1[r] * iv);
    }
    asm volatile("s_waitcnt lgkmcnt(0)" ::: "memory");
    __builtin_amdgcn_sched_barrier(0);
    {
      int row = lane >> 2, cc = lane & 3;
      bf16x8 ov = *(const bf16x8*)&ast[row * 40 + cc * 8];
      *(bf16x8*)(obase + (size_t)(q0 + row) * 256 + cc * 8) = ov;
    }
  }
}

// ---------------------------------------------------------------- LayerNorm
__global__ __launch_bounds__(256) void ln_kernel(
    const float* __restrict__ resid, const float* __restrict__ delta,
    const float* __restrict__ sc, const float* __restrict__ bi,
    float* __restrict__ out32, bf16* __restrict__ out16) {
  int row = blockIdx.x * 4 + (threadIdx.x >> 6);
  int lane = threadIdx.x & 63;
  const float4 x4 = *(const float4*)(resid + (size_t)row * 256 + lane * 4);
  const float4 d4 = *(const float4*)(delta + (size_t)row * 256 + lane * 4);
  float v[4] = {x4.x + d4.x, x4.y + d4.y, x4.z + d4.z, x4.w + d4.w};
  float s1 = v[0] + v[1] + v[2] + v[3];
  float s2 = v[0] * v[0] + v[1] * v[1] + v[2] * v[2] + v[3] * v[3];
#pragma unroll
  for (int off = 32; off; off >>= 1) {
    s1 += __shfl_xor(s1, off);
    s2 += __shfl_xor(s2, off);
  }
  float mu = s1 * (1.f / 256.f);
  float var = s2 * (1.f / 256.f) - mu * mu;
  float rs = rsqrtf(var + 1e-5f);
  const float4 sc4 = *(const float4*)(sc + lane * 4);
  const float4 bi4 = *(const float4*)(bi + lane * 4);
  float y0 = (v[0] - mu) * rs * sc4.x + bi4.x;
  float y1 = (v[1] - mu) * rs * sc4.y + bi4.y;
  float y2 = (v[2] - mu) * rs * sc4.z + bi4.z;
  float y3 = (v[3] - mu) * rs * sc4.w + bi4.w;
  float4 o4; o4.x = y0; o4.y = y1; o4.z = y2; o4.w = y3;
  *(float4*)(out32 + (size_t)row * 256 + lane * 4) = o4;
  bf16x4 ov = {(bf16)y0, (bf16)y1, (bf16)y2, (bf16)y3};
  *(bf16x4*)(out16 + (size_t)row * 256 + lane * 4) = ov;
}

// ---------------------------------------------------------------- host
extern "C" void kernel_launch(void* const* d_in, const int* in_sizes, int n_in,
                              void* d_out, int out_size, void* d_ws, size_t ws_size,
                              hipStream_t stream) {
  const float* q_embed  = (const float*)d_in[0];
  const float* qa_embed = (const float*)d_in[1];
  const float* Wk = (const float*)d_in[2];
  const float* bk = (const float*)d_in[3];
  const float* Wv = (const float*)d_in[4];
  const float* bv = (const float*)d_in[5];
  const float* Wo = (const float*)d_in[6];
  const float* bo = (const float*)d_in[7];
  const float* gammas = (const float*)d_in[8];
  const float* ln1_s = (const float*)d_in[9];
  const float* ln1_b = (const float*)d_in[10];
  const float* W1 = (const float*)d_in[11];
  const float* b1 = (const float*)d_in[12];
  const float* W2 = (const float*)d_in[13];
  const float* b2 = (const float*)d_in[14];
  const float* ln2_s = (const float*)d_in[15];
  const float* ln2_b = (const float*)d_in[16];
  float* out = (float*)d_out;

  char* ws = (char*)d_ws;
  float* y32 = (float*)(ws);
  float* x32 = (float*)(ws + ((size_t)16 << 20));
  bf16* y16  = (bf16*)(ws + ((size_t)32 << 20));
  bf16* x16  = (bf16*)(ws + ((size_t)40 << 20));
  bf16* khb  = (bf16*)(ws + ((size_t)48 << 20));
  bf16* vhb  = (bf16*)(ws + ((size_t)56 << 20));
  bf16* o16  = (bf16*)(ws + ((size_t)64 << 20));
  float* tmp32 = (float*)(ws + ((size_t)72 << 20));
  bf16* h116 = (bf16*)(ws + ((size_t)88 << 20));     // [M,1024] bf16 = 32 MB
  bf16* Wkt  = (bf16*)(ws + ((size_t)122 << 20));
  bf16* Wvt  = Wkt + 6 * 65536;
  bf16* Wot  = Wvt + 6 * 65536;
  bf16* W1t  = Wot + 6 * 65536;      // [N=1024][K=256] per layer
  bf16* W2t  = W1t + 6 * 262144;     // [N=256][K=1024] per layer

  transpose_cvt_all<<<dim3(16, 16, 30), 256, 0, stream>>>(Wk, Wv, Wo, W1, W2,
                                                          Wkt, Wvt, Wot, W1t, W2t);
  cvt_copy2_kernel<<<dim3(4096, 2), 256, 0, stream>>>(q_embed, x32, x16,
                                                      qa_embed, y32, y16, Mc * Dc / 4);

  const dim3 g256(128, 2);
  for (int i = 0; i < 6; ++i) {
    const bool first = (i < 2);
    const bool strict = (i == 3 || i == 5);   // mask_flag==0 layers
    const bool pos = first || strict;         // apply_pos
    bf16* in16 = first ? y16 : x16;           // q/k input (kq_same)
    bf16* v16  = (first || strict) ? y16 : x16;
    float* res32 = first ? y32 : x32;

    gemm_kv_kernel<<<dim3(128, 4), 256, 0, stream>>>(
        in16, Wkt + (size_t)i * 65536, bk + i * 256, khb,
        v16, Wvt + (size_t)i * 65536, bv + i * 256, vhb, 256, 256);
    attn_kernel<<<dim3(256, 2), 512, 0, stream>>>(khb, vhb, gammas + i * 8, o16, strict ? 0 : 1);
    gemm_bias_kernel<0, float><<<g256, 256, 0, stream>>>(o16, Wot + (size_t)i * 65536, bo + i * 256, tmp32, 256, 256);
    ln_kernel<<<4096, 256, 0, stream>>>(res32, tmp32, ln1_s + i * 256, ln1_b + i * 256, res32, in16);
    if (pos) {
      gemm_bias_kernel<1, bf16><<<dim3(128, 8), 256, 0, stream>>>(in16, W1t + (size_t)i * 262144, b1 + i * 1024, h116, 256, 1024);
      gemm_bias_kernel<0, float><<<g256, 256, 0, stream>>>(h116, W2t + (size_t)i * 262144, b2 + i * 256, tmp32, 1024, 256);
      float* fin = (i == 5) ? out : res32;
      ln_kernel<<<4096, 256, 0, stream>>>(res32, tmp32, ln2_s + i * 256, ln2_b + i * 256, fin, in16);
    }
  }
}

// Round 3
// 771.895 us; speedup vs baseline: 1.3358x; 1.0423x over previous
//
#include <hip/hip_runtime.h>
#include <cstdint>
#include <cstddef>

// ---------------------------------------------------------------------------
// AKT-style 6-layer transformer forward on MI355X (gfx950).  Round 3:
//  - attention: NO per-lane state arrays (R1/R2 spilled to scratch: VGPR=52,
//    ~64MB/dispatch spill traffic). Pass A computes softmax total via
//    recomputed QK^T; pass B recomputes scores per tile and fuses
//    scan+decay+PV per 2-tile chunk. Balanced wave pairing, coalesced stores.
// ---------------------------------------------------------------------------

#define AS1 __attribute__((address_space(1)))
#define AS3 __attribute__((address_space(3)))

typedef __bf16 bf16;
typedef __bf16 bf16x8 __attribute__((ext_vector_type(8)));
typedef __bf16 bf16x4 __attribute__((ext_vector_type(4)));
typedef float  f32x4  __attribute__((ext_vector_type(4)));
typedef unsigned int u32;

static constexpr int Bc = 32, Sc = 512, Dc = 256, Hc = 8, DKc = 32, DFFc = 1024;
static constexpr int Mc = Bc * Sc; // 16384 rows

// ---------------------------------------------------------------- converts
__global__ void cvt_copy2_kernel(const float* __restrict__ s0, float* __restrict__ da32,
                                 bf16* __restrict__ da16, const float* __restrict__ s1,
                                 float* __restrict__ db32, bf16* __restrict__ db16, int n4) {
  const float* s = blockIdx.y ? s1 : s0;
  float* d32 = blockIdx.y ? db32 : da32;
  bf16* d16 = blockIdx.y ? db16 : da16;
  int i = blockIdx.x * blockDim.x + threadIdx.x;
  if (i < n4) {
    float4 v = ((const float4*)s)[i];
    ((float4*)d32)[i] = v;
    bf16x4 hx = {(bf16)v.x, (bf16)v.y, (bf16)v.z, (bf16)v.w};
    ((bf16x4*)d16)[i] = hx;
  }
}

// Tiled transpose+cvt for all 5 weights: W[K,N] fp32 -> Wt[N,K] bf16.
__global__ __launch_bounds__(256) void transpose_cvt_all(
    const float* __restrict__ Wk, const float* __restrict__ Wv, const float* __restrict__ Wo,
    const float* __restrict__ W1, const float* __restrict__ W2,
    bf16* __restrict__ Wkt, bf16* __restrict__ Wvt, bf16* __restrict__ Wot,
    bf16* __restrict__ W1t, bf16* __restrict__ W2t) {
  int z = blockIdx.z;
  int layer = z % 6, w = z / 6;
  const float* src; bf16* dst; int K, N;
  switch (w) {
    case 0: src = Wk; dst = Wkt; K = 256; N = 256; break;
    case 1: src = Wv; dst = Wvt; K = 256; N = 256; break;
    case 2: src = Wo; dst = Wot; K = 256; N = 256; break;
    case 3: src = W1; dst = W1t; K = 256; N = 1024; break;
    default: src = W2; dst = W2t; K = 1024; N = 256; break;
  }
  int k0 = blockIdx.x * 64, n0 = blockIdx.y * 64;
  if (k0 >= K || n0 >= N) return;
  src += (size_t)layer * K * N;
  dst += (size_t)layer * K * N;
  __shared__ bf16 t[64][68];
  int tid = threadIdx.x;
  int rr = tid >> 4;         // 0..15
  int c4 = (tid & 15) * 4;   // 0..60
#pragma unroll
  for (int p = 0; p < 4; ++p) {
    int k = rr + p * 16;
    float4 v = *(const float4*)(src + (size_t)(k0 + k) * N + n0 + c4);
    t[c4 + 0][k] = (bf16)v.x;
    t[c4 + 1][k] = (bf16)v.y;
    t[c4 + 2][k] = (bf16)v.z;
    t[c4 + 3][k] = (bf16)v.w;
  }
  __syncthreads();
#pragma unroll
  for (int p = 0; p < 4; ++p) {
    int nl = rr + p * 16;
    bf16x4 o4 = *(const bf16x4*)&t[nl][c4];
    *(bf16x4*)(dst + (size_t)(n0 + nl) * K + k0 + c4) = o4;
  }
}

// ---------------------------------------------------------------- GEMM
// C[M,N] = A[M,K](bf16) @ Bt[N,K]^T (bf16) + bias, optional relu.
template <int RELU, typename OUT_T>
__device__ __forceinline__ void gemm_body(
    const bf16* __restrict__ A, const bf16* __restrict__ Bt,
    const float* __restrict__ bias, OUT_T* __restrict__ C,
    int K, int N, int m0, int n0, bf16* As, bf16* Bs) {
  const int tid = threadIdx.x;
  const int lane = tid & 63;
  const int wid = tid >> 6;
  const int wm = (wid >> 1) * 64;
  const int wn = (wid & 1) * 64;
  f32x4 acc[4][4] = {};

  const int o1 = wid * 1024 + lane * 16;
  const int o2 = o1 + 4096;
  const int r1 = o1 >> 6, c1 = o1 & 63;
  const int r2 = o2 >> 6, c2 = o2 & 63;
  const char* Ab = (const char*)A;
  const char* Bb = (const char*)Bt;
  const size_t stride = (size_t)K * 2;

  for (int k0 = 0; k0 < K; k0 += 32) {
    const char* a1 = Ab + (size_t)(m0 + r1) * stride + (size_t)k0 * 2 + c1;
    const char* a2 = Ab + (size_t)(m0 + r2) * stride + (size_t)k0 * 2 + c2;
    const char* b1 = Bb + (size_t)(n0 + r1) * stride + (size_t)k0 * 2 + c1;
    const char* b2 = Bb + (size_t)(n0 + r2) * stride + (size_t)k0 * 2 + c2;
    __builtin_amdgcn_global_load_lds((const AS1 u32*)a1, (AS3 u32*)((char*)As + wid * 1024), 16, 0, 0);
    __builtin_amdgcn_global_load_lds((const AS1 u32*)a2, (AS3 u32*)((char*)As + wid * 1024 + 4096), 16, 0, 0);
    __builtin_amdgcn_global_load_lds((const AS1 u32*)b1, (AS3 u32*)((char*)Bs + wid * 1024), 16, 0, 0);
    __builtin_amdgcn_global_load_lds((const AS1 u32*)b2, (AS3 u32*)((char*)Bs + wid * 1024 + 4096), 16, 0, 0);
    asm volatile("s_waitcnt vmcnt(0)" ::: "memory");
    __syncthreads();

    const int rr = lane & 15;
    const int g8 = (lane >> 4) * 8;
    bf16x8 af[4], bfr[4];
#pragma unroll
    for (int i = 0; i < 4; ++i) {
      af[i]  = *(const bf16x8*)&As[(wm + i * 16 + rr) * 32 + g8];
      bfr[i] = *(const bf16x8*)&Bs[(wn + i * 16 + rr) * 32 + g8];
    }
#pragma unroll
    for (int mi = 0; mi < 4; ++mi)
#pragma unroll
      for (int ni = 0; ni < 4; ++ni)
        acc[mi][ni] = __builtin_amdgcn_mfma_f32_16x16x32_bf16(af[mi], bfr[ni], acc[mi][ni], 0, 0, 0);
    __syncthreads();
  }

  const int rr = lane & 15;
  const int g4 = (lane >> 4) * 4;
  float bv[4];
#pragma unroll
  for (int ni = 0; ni < 4; ++ni) bv[ni] = bias[n0 + wn + ni * 16 + rr];
#pragma unroll
  for (int mi = 0; mi < 4; ++mi)
#pragma unroll
    for (int ni = 0; ni < 4; ++ni)
#pragma unroll
      for (int r = 0; r < 4; ++r) {
        float v = acc[mi][ni][r] + bv[ni];
        if (RELU) v = fmaxf(v, 0.f);
        int row = m0 + wm + mi * 16 + g4 + r;
        int col = n0 + wn + ni * 16 + rr;
        C[(size_t)row * N + col] = (OUT_T)v;
      }
}

template <int RELU, typename OUT_T>
__global__ __launch_bounds__(256) void gemm_bias_kernel(
    const bf16* __restrict__ A, const bf16* __restrict__ Bt,
    const float* __restrict__ bias, OUT_T* __restrict__ C, int K, int N) {
  __shared__ bf16 As[128 * 32];
  __shared__ bf16 Bs[128 * 32];
  gemm_body<RELU, OUT_T>(A, Bt, bias, C, K, N, blockIdx.x * 128, blockIdx.y * 128, As, Bs);
}

// K and V projections in one launch: blockIdx.y 0..3, y>>1 selects K/V set.
__global__ __launch_bounds__(256) void gemm_kv_kernel(
    const bf16* __restrict__ A0, const bf16* __restrict__ Bt0,
    const float* __restrict__ b0, bf16* __restrict__ C0,
    const bf16* __restrict__ A1, const bf16* __restrict__ Bt1,
    const float* __restrict__ b1, bf16* __restrict__ C1, int K, int N) {
  __shared__ bf16 As[128 * 32];
  __shared__ bf16 Bs[128 * 32];
  int sel = blockIdx.y >> 1;
  gemm_body<0, bf16>(sel ? A1 : A0, sel ? Bt1 : Bt0, sel ? b1 : b0, sel ? C1 : C0,
                     K, N, blockIdx.x * 128, (blockIdx.y & 1) * 128, As, Bs);
}

// ---------------------------------------------------------------- attention
// Per block: one (b,h), one parity-half of q-blocks. 512 threads, 8 waves.
// Wave w handles q-blocks {half+2w, half+2(15-w)} (balanced tile counts).
// No per-lane state arrays: pass A computes total via recompute; pass B
// recomputes scores per tile and fuses scan/decay/PV per 2-tile chunk.
__global__ __launch_bounds__(512, 4) void attn_kernel(
    const bf16* __restrict__ kh, const bf16* __restrict__ vh,
    const float* __restrict__ gam, bf16* __restrict__ o, int incl_diag) {
  __shared__ bf16 Klds[512 * 32];      // [j][dk] linear (global_load_lds)
  __shared__ bf16 Vt[32 * 520];        // [dk][j], pad 520
  __shared__ bf16 astage[8][16 * 40];  // per-wave [16 q][32 j] pad 40

  const int tid = threadIdx.x;
  const int lane = tid & 63;
  const int wid = tid >> 6;
  const int bh = blockIdx.x;
  const int half = blockIdx.y;
  const int b = bh >> 3, h = bh & 7;
  const bf16* kbase = kh + ((size_t)b * 4096 + h) * 32;
  const bf16* vbase = vh + ((size_t)b * 4096 + h) * 32;
  bf16* obase = o + ((size_t)b * 4096 + h) * 32;

  // stage K: 32 KB via global_load_lds (linear [512][32] bf16, row = 64 B)
#pragma unroll
  for (int it = 0; it < 4; ++it) {
    int off = it * 8192 + wid * 1024 + lane * 16;
    int j = off >> 6, cc = off & 63;
    const char* gsrc = (const char*)kbase + (size_t)j * 512 + cc;
    __builtin_amdgcn_global_load_lds((const AS1 u32*)gsrc,
                                     (AS3 u32*)((char*)Klds + it * 8192 + wid * 1024), 16, 0, 0);
  }
  // stage V transposed with b64 LDS writes: thread owns j-quad x 8-dk chunk
  {
    int u = tid & 127;   // j quad index (j0 = 4u)
    int cg = tid >> 7;   // dk chunk 0..3
    const bf16* vb = vbase + (size_t)(4 * u) * 256 + cg * 8;
    bf16x8 r0 = *(const bf16x8*)(vb);
    bf16x8 r1 = *(const bf16x8*)(vb + 256);
    bf16x8 r2 = *(const bf16x8*)(vb + 512);
    bf16x8 r3 = *(const bf16x8*)(vb + 768);
#pragma unroll
    for (int e = 0; e < 8; ++e) {
      bf16x4 w4 = {r0[e], r1[e], r2[e], r3[e]};
      *(bf16x4*)&Vt[(size_t)(cg * 8 + e) * 520 + 4 * u] = w4;
    }
  }
  asm volatile("s_waitcnt vmcnt(0)" ::: "memory");
  __syncthreads();

  const float scale = 0.17677669529663687f;  // 1/sqrt(32)
  float gm = gam[h];
  float gneg = -(fmaxf(gm, 0.f) + log1pf(__expf(-fabsf(gm))));

  const int q = lane & 15;
  const int g = lane >> 4;
  bf16* ast = &astage[wid][0];

#pragma unroll
  for (int pass = 0; pass < 2; ++pass) {
    const int qb = half + 2 * (pass ? (15 - wid) : wid);  // balanced pairing
    const int q0 = qb * 16;
    const int qr = q0 + q;
    const int qlim = incl_diag ? qr : qr - 1;
    const int jtReal = qb + 1;
    const int jtN = (jtReal + 1) & ~1;  // even # of 16-j tiles

    const bf16x8 qf = *(const bf16x8*)&Klds[(size_t)(q0 + q) * 32 + g * 8];

    // Pass A: softmax total (unnormalized; |s|<~6 so no max-sub needed)
    float tot = 0.f;
    for (int jt = 0; jt < jtReal; ++jt) {
      bf16x8 af = *(const bf16x8*)&Klds[(size_t)(jt * 16 + q) * 32 + g * 8];
      f32x4 c = {0.f, 0.f, 0.f, 0.f};
      c = __builtin_amdgcn_mfma_f32_16x16x32_bf16(af, qf, c, 0, 0, 0);
#pragma unroll
      for (int r = 0; r < 4; ++r) {
        int j = jt * 16 + 4 * g + r;
        tot += (j <= qlim) ? __expf(c[r] * scale) : 0.f;
      }
    }
    tot += __shfl_xor(tot, 16);
    tot += __shfl_xor(tot, 32);
    const float itot = tot > 0.f ? 1.f / tot : 0.f;

    // Pass B: recompute scores; scan cumsum + decay + 2nd softmax + PV, fused
    f32x4 oacc0 = {0.f, 0.f, 0.f, 0.f}, oacc1 = {0.f, 0.f, 0.f, 0.f};
    float run = 0.f, sum2 = 0.f;
    const int nch = jtN >> 1;
    for (int cch = 0; cch < nch; ++cch) {
#pragma unroll
      for (int hf = 0; hf < 2; ++hf) {
        const int jt = cch * 2 + hf;
        bf16x4 pk = {(bf16)0.f, (bf16)0.f, (bf16)0.f, (bf16)0.f};
        if (jt < jtReal) {
          bf16x8 af = *(const bf16x8*)&Klds[(size_t)(jt * 16 + q) * 32 + g * 8];
          f32x4 c = {0.f, 0.f, 0.f, 0.f};
          c = __builtin_amdgcn_mfma_f32_16x16x32_bf16(af, qf, c, 0, 0, 0);
          float su[4], ee[4];
#pragma unroll
          for (int r = 0; r < 4; ++r) {
            int j = jt * 16 + 4 * g + r;
            su[r] = c[r] * scale;
            ee[r] = (j <= qlim) ? __expf(su[r]) : 0.f;
          }
          float lcs[4];
          lcs[0] = ee[0]; lcs[1] = lcs[0] + ee[1]; lcs[2] = lcs[1] + ee[2]; lcs[3] = lcs[2] + ee[3];
          float sc = lcs[3];
          float u1 = __shfl_up(sc, 16); if (g >= 1) sc += u1;
          float u2 = __shfl_up(sc, 32); if (g >= 2) sc += u2;
          float excl = run + sc - lcs[3];
          run += __shfl(sc, q + 48);
#pragma unroll
          for (int r = 0; r < 4; ++r) {
            int j = jt * 16 + 4 * g + r;
            float cum = excl + lcs[r];
            float pos = (float)(qr - j);
            float d2 = (1.f - cum * itot) * pos;
            float dist = sqrtf(fmaxf(d2, 0.f));
            float eff = fminf(fmaxf(__expf(dist * gneg), 1e-5f), 1e5f);
            float pv = (j <= qlim) ? __expf(su[r] * eff) : 0.f;
            sum2 += pv;
            pk[r] = (bf16)pv;
          }
        }
        *(bf16x4*)&ast[q * 40 + hf * 16 + 4 * g] = pk;
      }
      asm volatile("s_waitcnt lgkmcnt(0)" ::: "memory");
      __builtin_amdgcn_sched_barrier(0);
      bf16x8 afr = *(const bf16x8*)&ast[q * 40 + 8 * g];
      bf16x8 vb0 = *(const bf16x8*)&Vt[(size_t)q * 520 + cch * 32 + 8 * g];
      bf16x8 vb1 = *(const bf16x8*)&Vt[(size_t)(q + 16) * 520 + cch * 32 + 8 * g];
      oacc0 = __builtin_amdgcn_mfma_f32_16x16x32_bf16(afr, vb0, oacc0, 0, 0, 0);
      oacc1 = __builtin_amdgcn_mfma_f32_16x16x32_bf16(afr, vb1, oacc1, 0, 0, 0);
    }
    sum2 += __shfl_xor(sum2, 16);
    sum2 += __shfl_xor(sum2, 32);
    const float inv2 = sum2 > 0.f ? 1.f / sum2 : 0.f;  // 0 => zero_pad row

    // epilogue: scale, restage in LDS, coalesced 16B stores
#pragma unroll
    for (int r = 0; r < 4; ++r) {
      float iv = __shfl(inv2, 4 * g + r);
      int rl = 4 * g + r;
      ast[rl * 40 + q] = (bf16)(oacc0[r] * iv);
      ast[rl * 40 + 16 + q] = (bf16)(oacc1[r] * iv);
    }
    asm volatile("s_waitcnt lgkmcnt(0)" ::: "memory");
    __builtin_amdgcn_sched_barrier(0);
    {
      int row = lane >> 2, cc = lane & 3;
      bf16x8 ov = *(const bf16x8*)&ast[row * 40 + cc * 8];
      *(bf16x8*)(obase + (size_t)(q0 + row) * 256 + cc * 8) = ov;
    }
  }
}

// ---------------------------------------------------------------- LayerNorm
__global__ __launch_bounds__(256) void ln_kernel(
    const float* __restrict__ resid, const float* __restrict__ delta,
    const float* __restrict__ sc, const float* __restrict__ bi,
    float* __restrict__ out32, bf16* __restrict__ out16) {
  int row = blockIdx.x * 4 + (threadIdx.x >> 6);
  int lane = threadIdx.x & 63;
  const float4 x4 = *(const float4*)(resid + (size_t)row * 256 + lane * 4);
  const float4 d4 = *(const float4*)(delta + (size_t)row * 256 + lane * 4);
  float v[4] = {x4.x + d4.x, x4.y + d4.y, x4.z + d4.z, x4.w + d4.w};
  float s1 = v[0] + v[1] + v[2] + v[3];
  float s2 = v[0] * v[0] + v[1] * v[1] + v[2] * v[2] + v[3] * v[3];
#pragma unroll
  for (int off = 32; off; off >>= 1) {
    s1 += __shfl_xor(s1, off);
    s2 += __shfl_xor(s2, off);
  }
  float mu = s1 * (1.f / 256.f);
  float var = s2 * (1.f / 256.f) - mu * mu;
  float rs = rsqrtf(var + 1e-5f);
  const float4 sc4 = *(const float4*)(sc + lane * 4);
  const float4 bi4 = *(const float4*)(bi + lane * 4);
  float y0 = (v[0] - mu) * rs * sc4.x + bi4.x;
  float y1 = (v[1] - mu) * rs * sc4.y + bi4.y;
  float y2 = (v[2] - mu) * rs * sc4.z + bi4.z;
  float y3 = (v[3] - mu) * rs * sc4.w + bi4.w;
  float4 o4; o4.x = y0; o4.y = y1; o4.z = y2; o4.w = y3;
  *(float4*)(out32 + (size_t)row * 256 + lane * 4) = o4;
  bf16x4 ov = {(bf16)y0, (bf16)y1, (bf16)y2, (bf16)y3};
  *(bf16x4*)(out16 + (size_t)row * 256 + lane * 4) = ov;
}

// ---------------------------------------------------------------- host
extern "C" void kernel_launch(void* const* d_in, const int* in_sizes, int n_in,
                              void* d_out, int out_size, void* d_ws, size_t ws_size,
                              hipStream_t stream) {
  const float* q_embed  = (const float*)d_in[0];
  const float* qa_embed = (const float*)d_in[1];
  const float* Wk = (const float*)d_in[2];
  const float* bk = (const float*)d_in[3];
  const float* Wv = (const float*)d_in[4];
  const float* bv = (const float*)d_in[5];
  const float* Wo = (const float*)d_in[6];
  const float* bo = (const float*)d_in[7];
  const float* gammas = (const float*)d_in[8];
  const float* ln1_s = (const float*)d_in[9];
  const float* ln1_b = (const float*)d_in[10];
  const float* W1 = (const float*)d_in[11];
  const float* b1 = (const float*)d_in[12];
  const float* W2 = (const float*)d_in[13];
  const float* b2 = (const float*)d_in[14];
  const float* ln2_s = (const float*)d_in[15];
  const float* ln2_b = (const float*)d_in[16];
  float* out = (float*)d_out;

  char* ws = (char*)d_ws;
  float* y32 = (float*)(ws);
  float* x32 = (float*)(ws + ((size_t)16 << 20));
  bf16* y16  = (bf16*)(ws + ((size_t)32 << 20));
  bf16* x16  = (bf16*)(ws + ((size_t)40 << 20));
  bf16* khb  = (bf16*)(ws + ((size_t)48 << 20));
  bf16* vhb  = (bf16*)(ws + ((size_t)56 << 20));
  bf16* o16  = (bf16*)(ws + ((size_t)64 << 20));
  float* tmp32 = (float*)(ws + ((size_t)72 << 20));
  bf16* h116 = (bf16*)(ws + ((size_t)88 << 20));     // [M,1024] bf16 = 32 MB
  bf16* Wkt  = (bf16*)(ws + ((size_t)122 << 20));
  bf16* Wvt  = Wkt + 6 * 65536;
  bf16* Wot  = Wvt + 6 * 65536;
  bf16* W1t  = Wot + 6 * 65536;      // [N=1024][K=256] per layer
  bf16* W2t  = W1t + 6 * 262144;     // [N=256][K=1024] per layer

  transpose_cvt_all<<<dim3(16, 16, 30), 256, 0, stream>>>(Wk, Wv, Wo, W1, W2,
                                                          Wkt, Wvt, Wot, W1t, W2t);
  cvt_copy2_kernel<<<dim3(4096, 2), 256, 0, stream>>>(q_embed, x32, x16,
                                                      qa_embed, y32, y16, Mc * Dc / 4);

  const dim3 g256(128, 2);
  for (int i = 0; i < 6; ++i) {
    const bool first = (i < 2);
    const bool strict = (i == 3 || i == 5);   // mask_flag==0 layers
    const bool pos = first || strict;         // apply_pos
    bf16* in16 = first ? y16 : x16;           // q/k input (kq_same)
    bf16* v16  = (first || strict) ? y16 : x16;
    float* res32 = first ? y32 : x32;

    gemm_kv_kernel<<<dim3(128, 4), 256, 0, stream>>>(
        in16, Wkt + (size_t)i * 65536, bk + i * 256, khb,
        v16, Wvt + (size_t)i * 65536, bv + i * 256, vhb, 256, 256);
    attn_kernel<<<dim3(256, 2), 512, 0, stream>>>(khb, vhb, gammas + i * 8, o16, strict ? 0 : 1);
    gemm_bias_kernel<0, float><<<g256, 256, 0, stream>>>(o16, Wot + (size_t)i * 65536, bo + i * 256, tmp32, 256, 256);
    ln_kernel<<<4096, 256, 0, stream>>>(res32, tmp32, ln1_s + i * 256, ln1_b + i * 256, res32, in16);
    if (pos) {
      gemm_bias_kernel<1, bf16><<<dim3(128, 8), 256, 0, stream>>>(in16, W1t + (size_t)i * 262144, b1 + i * 1024, h116, 256, 1024);
      gemm_bias_kernel<0, float><<<g256, 256, 0, stream>>>(h116, W2t + (size_t)i * 262144, b2 + i * 256, tmp32, 1024, 256);
      float* fin = (i == 5) ? out : res32;
      ln_kernel<<<4096, 256, 0, stream>>>(res32, tmp32, ln2_s + i * 256, ln2_b + i * 256, fin, in16);
    }
  }
}